// Round 2
// baseline (843.195 us; speedup 1.0000x reference)
//
#include <hip/hip_runtime.h>
#include <hip/hip_bf16.h>

// Problem constants (from reference)
#define BB 4096
#define DD 256
#define LL 4
#define CC 2048
#define NN 100000

typedef unsigned int uint32;

__device__ __forceinline__ uint32 f2ord(float f) {
    uint32 u = __float_as_uint(f);
    return (u & 0x80000000u) ? ~u : (u | 0x80000000u);
}
__device__ __forceinline__ float ord2f(uint32 u) {
    u = (u & 0x80000000u) ? (u & 0x7FFFFFFFu) : ~u;
    return __uint_as_float(u);
}

// ---------------- Kernel 1: inverse L2 norms (one wave per row of 256) ----------------
__global__ __launch_bounds__(256) void inv_norms(const float* __restrict__ src,
                                                 float* __restrict__ dst, int nrows) {
    int row = blockIdx.x * 4 + (threadIdx.x >> 6);
    int lane = threadIdx.x & 63;
    if (row >= nrows) return;
    float4 v = *reinterpret_cast<const float4*>(src + (size_t)row * DD + lane * 4);
    float ss = v.x * v.x + v.y * v.y + v.z * v.z + v.w * v.w;
    #pragma unroll
    for (int m = 1; m < 64; m <<= 1) ss += __shfl_xor(ss, m);
    if (lane == 0) dst[row] = 1.0f / fmaxf(sqrtf(ss), 1e-12f);
}

// ---------------- Kernel 2: prep (positive labels per (b,l), init keys) ----------------
__global__ __launch_bounds__(256) void prep(const int* __restrict__ labels_per_eps,
                                            const int* __restrict__ local_indices,
                                            int* __restrict__ pos_col,
                                            uint32* __restrict__ ap_key,
                                            uint32* __restrict__ an_key) {
    int t = blockIdx.x * 256 + threadIdx.x;   // 0 .. B*L-1
    int b = t >> 2, l = t & 3;
    pos_col[t] = labels_per_eps[l * NN + local_indices[b]];
    if (t < BB) {
        ap_key[t] = f2ord(2.0f);    // running min over positive sims
        an_key[t] = f2ord(-2.0f);   // running max over negative sims
    }
}

// ---------------- Kernel 3: fused GEMM + min/max reduction (broadcast-A form) -------
// Block: 256 threads = 4 waves. lane <-> centroid column (64 cols/tile);
// wave w owns anchor rows 16w..16w+15 -> acc[16] per lane.
// Per kg step: B-fragment = 1 float4/lane (conflict-free via XOR slot);
// A-fragments = 16 wave-uniform ds_read_b128 (hardware broadcast, ~free).
// -> LDS ~10 cyc/wave/kg vs VALU 128 cyc -> VALU-bound.
// Grid: (B/64, 16); blockIdx.y picks a 512-col quarter-level; ct loops 8x64 cols.
// Normalization folded in at staging time (scale rows by 1/||a||, cols by 1/||c||).
__global__ __launch_bounds__(256, 3) void main_k(const float* __restrict__ A,
                                                 const float* __restrict__ Cm,
                                                 const float* __restrict__ inv_a,
                                                 const float* __restrict__ inv_c,
                                                 const int* __restrict__ clab,
                                                 const int* __restrict__ pos_col,
                                                 uint32* __restrict__ ap_key,
                                                 uint32* __restrict__ an_key) {
    __shared__ float4 As[64 * 17];   // [row][kg], stride 17 -> balanced write banks
    __shared__ float4 Bs[16 * 64];   // [kg][col ^ (kg&7)] -> conflict-free write+read

    const int tid = threadIdx.x;
    const int lane = tid & 63;
    const int wv = tid >> 6;              // 0..3
    const int mb = blockIdx.x * 64;       // anchor base
    const int cb0 = blockIdx.y * 512;     // flat centroid base (quarter level)
    const int lev = blockIdx.y >> 2;      // level of this whole block

    // positive label for each of this wave's 16 anchor rows at this level
    int pc[16];
    #pragma unroll
    for (int r = 0; r < 16; ++r) pc[r] = pos_col[(mb + wv * 16 + r) * LL + lev];

    float nmax[16], pmin[16];
    #pragma unroll
    for (int r = 0; r < 16; ++r) { nmax[r] = -2.f; pmin[r] = 2.f; }

    const int kgS = tid & 15;   // staging k-group
    const int rS = tid >> 4;    // staging row base (+16*i)

    float sa[4];
    #pragma unroll
    for (int i = 0; i < 4; ++i) sa[i] = inv_a[mb + rS + 16 * i];

    for (int ct = 0; ct < 8; ++ct) {
        const int colbase = cb0 + ct * 64;
        float sb[4];
        #pragma unroll
        for (int i = 0; i < 4; ++i) sb[i] = inv_c[colbase + rS + 16 * i];

        float acc[16];
        #pragma unroll
        for (int r = 0; r < 16; ++r) acc[r] = 0.f;

        for (int kc = 0; kc < DD; kc += 64) {
            __syncthreads();
            #pragma unroll
            for (int i = 0; i < 4; ++i) {
                int r = rS + 16 * i;
                float4 av = *reinterpret_cast<const float4*>(
                    A + (size_t)(mb + r) * DD + kc + kgS * 4);
                av.x *= sa[i]; av.y *= sa[i]; av.z *= sa[i]; av.w *= sa[i];
                As[r * 17 + kgS] = av;
                float4 bv = *reinterpret_cast<const float4*>(
                    Cm + (size_t)(colbase + r) * DD + kc + kgS * 4);
                bv.x *= sb[i]; bv.y *= sb[i]; bv.z *= sb[i]; bv.w *= sb[i];
                Bs[kgS * 64 + (r ^ (kgS & 7))] = bv;
            }
            __syncthreads();

            #pragma unroll
            for (int kg = 0; kg < 16; ++kg) {
                float4 b = Bs[kg * 64 + (lane ^ (kg & 7))];
                #pragma unroll
                for (int r = 0; r < 16; ++r) {
                    float4 a = As[(wv * 16 + r) * 17 + kg];  // wave-uniform -> broadcast
                    acc[r] = fmaf(a.x, b.x, acc[r]);
                    acc[r] = fmaf(a.y, b.y, acc[r]);
                    acc[r] = fmaf(a.z, b.z, acc[r]);
                    acc[r] = fmaf(a.w, b.w, acc[r]);
                }
            }
        }

        // epilogue: lane's column is colbase+lane; route sims to pos-min / neg-max
        int cl = clab[colbase + lane];
        #pragma unroll
        for (int r = 0; r < 16; ++r) {
            bool pos = (pc[r] == cl) && (pc[r] >= 0);
            if (pos) pmin[r] = fminf(pmin[r], acc[r]);
            else     nmax[r] = fmaxf(nmax[r], acc[r]);
        }
    }

    // reduce neg-max across the 64 lanes (cols) of the wave
    #pragma unroll
    for (int m = 1; m < 64; m <<= 1) {
        #pragma unroll
        for (int r = 0; r < 16; ++r)
            nmax[r] = fmaxf(nmax[r], __shfl_xor(nmax[r], m));
    }
    if (lane == 0) {
        #pragma unroll
        for (int r = 0; r < 16; ++r)
            atomicMax(&an_key[mb + wv * 16 + r], f2ord(nmax[r]));
    }
    // positives: at most one column per (row, level) matches -> rare, atomic direct
    #pragma unroll
    for (int r = 0; r < 16; ++r)
        if (pmin[r] < 1.5f) atomicMin(&ap_key[mb + wv * 16 + r], f2ord(pmin[r]));
}

// ---------------- Kernel 4: finalize loss ----------------
__global__ __launch_bounds__(256) void finalize(const uint32* __restrict__ ap_key,
                                                const uint32* __restrict__ an_key,
                                                float* __restrict__ out) {
    int tid = threadIdx.x;
    float sum = 0.f, cnt = 0.f;
    for (int b = tid; b < BB; b += 256) {
        float ap = ord2f(ap_key[b]);
        float an = ord2f(an_key[b]);
        if (ap < 1.5f) {  // has_pos (has_neg always true: >=8188 negatives/row)
            sum += fmaxf(an - ap + 0.2f, 0.f);
            cnt += 1.f;
        }
    }
    #pragma unroll
    for (int m = 1; m < 64; m <<= 1) {
        sum += __shfl_xor(sum, m);
        cnt += __shfl_xor(cnt, m);
    }
    __shared__ float s4[4], c4[4];
    int w = tid >> 6;
    if ((tid & 63) == 0) { s4[w] = sum; c4[w] = cnt; }
    __syncthreads();
    if (tid == 0) {
        float S = s4[0] + s4[1] + s4[2] + s4[3];
        float Cv = c4[0] + c4[1] + c4[2] + c4[3];
        out[0] = S / fmaxf(Cv, 1.f);
    }
}

extern "C" void kernel_launch(void* const* d_in, const int* in_sizes, int n_in,
                              void* d_out, int out_size, void* d_ws, size_t ws_size,
                              hipStream_t stream) {
    const float* anchors         = (const float*)d_in[0];   // B*D
    const float* centroids       = (const float*)d_in[1];   // L*C*D
    const int*   centroid_labels = (const int*)d_in[2];     // L*C
    const int*   labels_per_eps  = (const int*)d_in[3];     // L*N
    const int*   local_indices   = (const int*)d_in[4];     // B
    float* out = (float*)d_out;

    // workspace layout (~150 KB): inv_a | inv_c | pos_col | ap_key | an_key
    float*  inv_a  = (float*)d_ws;                          // B
    float*  inv_c  = inv_a + BB;                            // L*C
    int*    pos_col = (int*)(inv_c + LL * CC);              // B*L
    uint32* ap_key = (uint32*)(pos_col + BB * LL);          // B
    uint32* an_key = ap_key + BB;                           // B

    inv_norms<<<BB / 4, 256, 0, stream>>>(anchors, inv_a, BB);
    inv_norms<<<(LL * CC) / 4, 256, 0, stream>>>(centroids, inv_c, LL * CC);
    prep<<<(BB * LL) / 256, 256, 0, stream>>>(labels_per_eps, local_indices,
                                              pos_col, ap_key, an_key);
    main_k<<<dim3(BB / 64, 16), 256, 0, stream>>>(anchors, centroids, inv_a, inv_c,
                                                  centroid_labels, pos_col,
                                                  ap_key, an_key);
    finalize<<<1, 256, 0, stream>>>(ap_key, an_key, out);
}

// Round 3
// 693.601 us; speedup vs baseline: 1.2157x; 1.2157x over previous
//
#include <hip/hip_runtime.h>
#include <hip/hip_bf16.h>

// Problem constants (from reference)
#define BB 4096
#define DD 256
#define LL 4
#define CC 2048
#define NN 100000

typedef unsigned int uint32;

__device__ __forceinline__ uint32 f2ord(float f) {
    uint32 u = __float_as_uint(f);
    return (u & 0x80000000u) ? ~u : (u | 0x80000000u);
}
__device__ __forceinline__ float ord2f(uint32 u) {
    u = (u & 0x80000000u) ? (u & 0x7FFFFFFFu) : ~u;
    return __uint_as_float(u);
}

// ---------------- Kernel 1: inverse L2 norms (one wave per row of 256) ----------------
__global__ __launch_bounds__(256) void inv_norms(const float* __restrict__ src,
                                                 float* __restrict__ dst, int nrows) {
    int row = blockIdx.x * 4 + (threadIdx.x >> 6);
    int lane = threadIdx.x & 63;
    if (row >= nrows) return;
    float4 v = *reinterpret_cast<const float4*>(src + (size_t)row * DD + lane * 4);
    float ss = v.x * v.x + v.y * v.y + v.z * v.z + v.w * v.w;
    #pragma unroll
    for (int m = 1; m < 64; m <<= 1) ss += __shfl_xor(ss, m);
    if (lane == 0) dst[row] = 1.0f / fmaxf(sqrtf(ss), 1e-12f);
}

// ---------------- Kernel 2: prep (positive labels per (b,l), init keys) ----------------
__global__ __launch_bounds__(256) void prep(const int* __restrict__ labels_per_eps,
                                            const int* __restrict__ local_indices,
                                            int* __restrict__ pos_col,
                                            uint32* __restrict__ ap_key,
                                            uint32* __restrict__ an_key) {
    int t = blockIdx.x * 256 + threadIdx.x;   // 0 .. B*L-1
    int b = t >> 2, l = t & 3;
    pos_col[t] = labels_per_eps[l * NN + local_indices[b]];
    if (t < BB) {
        ap_key[t] = f2ord(2.0f);    // running min over positive sims
        an_key[t] = f2ord(-2.0f);   // running max over negative sims
    }
}

// ---------------- Kernel 3: fused GEMM + min/max reduction ----------------
// Grid (B/64, 128): x -> 64-anchor tile, y -> one 64-centroid flat tile.
// Block 256 = 4 waves; wave w owns anchor rows 16w..16w+15; lane <-> column.
// Hot-loop per-thread state is ONLY acc[16] (+ addresses): no arrays live
// across tiles -> no spill (round-2 lesson: WRITE_SIZE 336MB was scratch).
// LDS: As[64][17] float4 (write banks perfectly balanced via stride 17;
// reads wave-uniform -> broadcast). Bs[16][64] float4 with XOR slot
// (col ^ (kg&7)): write AND read both hit the 8-cycle b128 minimum.
// Normalization folded into the epilogue: s = acc * inv_a[row] * inv_c[col].
__global__ __launch_bounds__(256, 4) void main_k(const float* __restrict__ A,
                                                 const float* __restrict__ Cm,
                                                 const float* __restrict__ inv_a,
                                                 const float* __restrict__ inv_c,
                                                 const int* __restrict__ clab,
                                                 const int* __restrict__ pos_col,
                                                 uint32* __restrict__ ap_key,
                                                 uint32* __restrict__ an_key) {
    __shared__ float4 As[64 * 17];
    __shared__ float4 Bs[16 * 64];

    const int tid = threadIdx.x;
    const int lane = tid & 63;
    const int wv = tid >> 6;                 // 0..3
    const int mb = blockIdx.x * 64;          // anchor base
    const int colbase = blockIdx.y * 64;     // flat centroid base
    const int lev = colbase >> 11;           // colbase / 2048

    const int kgS = tid & 15;   // staging k-group (float4 index within 64-chunk)
    const int rS = tid >> 4;    // staging row base (+16*i)

    float acc[16];
    #pragma unroll
    for (int r = 0; r < 16; ++r) acc[r] = 0.f;

    for (int kc = 0; kc < DD; kc += 64) {
        __syncthreads();
        #pragma unroll
        for (int i = 0; i < 4; ++i) {
            int r = rS + 16 * i;
            As[r * 17 + kgS] = *reinterpret_cast<const float4*>(
                A + (size_t)(mb + r) * DD + kc + kgS * 4);
            Bs[kgS * 64 + (r ^ (kgS & 7))] = *reinterpret_cast<const float4*>(
                Cm + (size_t)(colbase + r) * DD + kc + kgS * 4);
        }
        __syncthreads();

        #pragma unroll
        for (int kg = 0; kg < 16; ++kg) {
            float4 b = Bs[kg * 64 + (lane ^ (kg & 7))];
            #pragma unroll
            for (int r = 0; r < 16; ++r) {
                float4 a = As[(wv * 16 + r) * 17 + kg];  // wave-uniform -> broadcast
                acc[r] = fmaf(a.x, b.x, acc[r]);
                acc[r] = fmaf(a.y, b.y, acc[r]);
                acc[r] = fmaf(a.z, b.z, acc[r]);
                acc[r] = fmaf(a.w, b.w, acc[r]);
            }
        }
    }

    // Epilogue: per row -> route to pos/neg, immediate 64-lane reduce, atomic.
    const float ic = inv_c[colbase + lane];
    const int cl = clab[colbase + lane];
    const int row0 = mb + wv * 16;
    #pragma unroll
    for (int r = 0; r < 16; ++r) {
        float s = acc[r] * inv_a[row0 + r] * ic;      // inv_a: wave-uniform load
        int pcr = pos_col[(row0 + r) * LL + lev];     // wave-uniform load
        bool pos = (pcr == cl) && (pcr >= 0);
        float nm = pos ? -2.f : s;
        #pragma unroll
        for (int m = 1; m < 64; m <<= 1) nm = fmaxf(nm, __shfl_xor(nm, m));
        if (lane == 0) atomicMax(&an_key[row0 + r], f2ord(nm));
        if (pos) atomicMin(&ap_key[row0 + r], f2ord(s));  // <=1 lane per row
    }
}

// ---------------- Kernel 4: finalize loss ----------------
__global__ __launch_bounds__(256) void finalize(const uint32* __restrict__ ap_key,
                                                const uint32* __restrict__ an_key,
                                                float* __restrict__ out) {
    int tid = threadIdx.x;
    float sum = 0.f, cnt = 0.f;
    for (int b = tid; b < BB; b += 256) {
        float ap = ord2f(ap_key[b]);
        float an = ord2f(an_key[b]);
        if (ap < 1.5f) {  // has_pos (has_neg always true: >=8188 negatives/row)
            sum += fmaxf(an - ap + 0.2f, 0.f);
            cnt += 1.f;
        }
    }
    #pragma unroll
    for (int m = 1; m < 64; m <<= 1) {
        sum += __shfl_xor(sum, m);
        cnt += __shfl_xor(cnt, m);
    }
    __shared__ float s4[4], c4[4];
    int w = tid >> 6;
    if ((tid & 63) == 0) { s4[w] = sum; c4[w] = cnt; }
    __syncthreads();
    if (tid == 0) {
        float S = s4[0] + s4[1] + s4[2] + s4[3];
        float Cv = c4[0] + c4[1] + c4[2] + c4[3];
        out[0] = S / fmaxf(Cv, 1.f);
    }
}

extern "C" void kernel_launch(void* const* d_in, const int* in_sizes, int n_in,
                              void* d_out, int out_size, void* d_ws, size_t ws_size,
                              hipStream_t stream) {
    const float* anchors         = (const float*)d_in[0];   // B*D
    const float* centroids       = (const float*)d_in[1];   // L*C*D
    const int*   centroid_labels = (const int*)d_in[2];     // L*C
    const int*   labels_per_eps  = (const int*)d_in[3];     // L*N
    const int*   local_indices   = (const int*)d_in[4];     // B
    float* out = (float*)d_out;

    // workspace layout (~150 KB): inv_a | inv_c | pos_col | ap_key | an_key
    float*  inv_a  = (float*)d_ws;                          // B
    float*  inv_c  = inv_a + BB;                            // L*C
    int*    pos_col = (int*)(inv_c + LL * CC);              // B*L
    uint32* ap_key = (uint32*)(pos_col + BB * LL);          // B
    uint32* an_key = ap_key + BB;                           // B

    inv_norms<<<BB / 4, 256, 0, stream>>>(anchors, inv_a, BB);
    inv_norms<<<(LL * CC) / 4, 256, 0, stream>>>(centroids, inv_c, LL * CC);
    prep<<<(BB * LL) / 256, 256, 0, stream>>>(labels_per_eps, local_indices,
                                              pos_col, ap_key, an_key);
    main_k<<<dim3(BB / 64, 128), 256, 0, stream>>>(anchors, centroids, inv_a, inv_c,
                                                   centroid_labels, pos_col,
                                                   ap_key, an_key);
    finalize<<<1, 256, 0, stream>>>(ap_key, an_key, out);
}

// Round 4
// 248.467 us; speedup vs baseline: 3.3936x; 2.7915x over previous
//
#include <hip/hip_runtime.h>
#include <hip/hip_bf16.h>

// Problem constants (from reference)
#define BB 4096
#define DD 256
#define LL 4
#define CC 2048
#define NN 100000

typedef unsigned int uint32;

using f32x16 = __attribute__((ext_vector_type(16))) float;
using bf16x8 = __attribute__((ext_vector_type(8))) __bf16;

__device__ __forceinline__ uint32 f2ord(float f) {
    uint32 u = __float_as_uint(f);
    return (u & 0x80000000u) ? ~u : (u | 0x80000000u);
}
__device__ __forceinline__ float ord2f(uint32 u) {
    u = (u & 0x80000000u) ? (u & 0x7FFFFFFFu) : ~u;
    return __uint_as_float(u);
}
__device__ __forceinline__ unsigned short bf16bits(float f) {
    __hip_bfloat16 h = __float2bfloat16(f);
    unsigned short b;
    __builtin_memcpy(&b, &h, 2);
    return b;
}

// ============================ FAST PATH (MFMA) ============================

// Normalize rows and split into bf16 hi + lo (x ~= hi + lo, err ~2^-17 rel).
__global__ __launch_bounds__(256) void convert_rows(const float* __restrict__ src,
                                                    unsigned short* __restrict__ hi,
                                                    unsigned short* __restrict__ lo,
                                                    int nrows) {
    int row = blockIdx.x * 4 + (threadIdx.x >> 6);
    int lane = threadIdx.x & 63;
    if (row >= nrows) return;
    float4 v = *reinterpret_cast<const float4*>(src + (size_t)row * DD + lane * 4);
    float ss = v.x * v.x + v.y * v.y + v.z * v.z + v.w * v.w;
    #pragma unroll
    for (int m = 1; m < 64; m <<= 1) ss += __shfl_xor(ss, m);
    float inv = 1.0f / fmaxf(sqrtf(ss), 1e-12f);
    float y0 = v.x * inv, y1 = v.y * inv, y2 = v.z * inv, y3 = v.w * inv;
    ushort4 h, l;
    h.x = bf16bits(y0); l.x = bf16bits(y0 - __bfloat162float(__float2bfloat16(y0)));
    h.y = bf16bits(y1); l.y = bf16bits(y1 - __bfloat162float(__float2bfloat16(y1)));
    h.z = bf16bits(y2); l.z = bf16bits(y2 - __bfloat162float(__float2bfloat16(y2)));
    h.w = bf16bits(y3); l.w = bf16bits(y3 - __bfloat162float(__float2bfloat16(y3)));
    *reinterpret_cast<ushort4*>(hi + (size_t)row * DD + lane * 4) = h;
    *reinterpret_cast<ushort4*>(lo + (size_t)row * DD + lane * 4) = l;
}

// pos_col stored [L][B] (level-major) to enable int4 loads in the epilogue.
__global__ __launch_bounds__(256) void prep_pos(const int* __restrict__ lpe,
                                                const int* __restrict__ li,
                                                int* __restrict__ pos_col) {
    int t = blockIdx.x * 256 + threadIdx.x;  // 0 .. 16383
    int l = t >> 12, b = t & 4095;
    pos_col[l * BB + b] = lpe[l * NN + li[b]];
}

// Fused 3-product MFMA GEMM + per-row pos-min / neg-max, atomic-free.
// Block tile 128(M)x128(N), BK=32, 4 waves in 2x2. Wave tile 64x64 =
// 2x2 frags of 32x32x16 bf16 MFMA; acc = 4x f32x16 = 64 VGPR.
// LDS 32KB: Ah|Al|Bh|Bl, each [128 rows][32 k] bf16 (64B rows) with a
// 16B-block XOR swizzle (blk ^ (row&3)) -> even 32-bank spread for both
// staging ds_write_b128 and fragment ds_read_b128 (verified by hand).
// A and B fragments are loaded with the SAME (lane-group,elem)->k map, so
// any hardware-internal k ordering cancels in the dot product; only the
// C/D layout (col=lane&31, row=(reg&3)+8*(reg>>2)+4*(lane>>5)) is assumed.
// Grid 2048 with 8-XCD supertile swizzle: each XCD works a 16x16 block
// region -> 2MB A + 2MB B working set = one XCD L2.
__global__ __launch_bounds__(256, 3) void mfma_main(
    const unsigned short* __restrict__ Ah, const unsigned short* __restrict__ Al,
    const unsigned short* __restrict__ Bh, const unsigned short* __restrict__ Bl,
    const int* __restrict__ clab, const int* __restrict__ pos_col,
    float* __restrict__ pn, float* __restrict__ pp) {
    __shared__ __align__(16) char smem[32768];

    const int tid = threadIdx.x;
    const int lane = tid & 63;
    const int w = tid >> 6;            // wave 0..3
    const int wr = w >> 1, wc = w & 1; // 2x2 wave grid

    // XCD supertile swizzle (2048 % 8 == 0, bijective)
    const int bid = blockIdx.x;
    const int xcd = bid & 7, inner = bid >> 3;
    const int bx = (xcd & 1) * 16 + (inner & 15);   // 0..31 (M tiles)
    const int by = (xcd >> 1) * 16 + (inner >> 4);  // 0..63 (N tiles)
    const int mb = bx * 128, nb = by * 128;
    const int lev = nb >> 11;

    // ---- staging addresses (8 loads/wave/chunk: 2 per array) ----
    const int rl = lane >> 2;  // row-within-16
    const int kb = lane & 3;   // 16B block within 64B row
    const unsigned short* gsrc[8];
    int lof[8];
    #pragma unroll
    for (int a = 0; a < 4; ++a) {
        const unsigned short* base = (a == 0) ? Ah : (a == 1) ? Al : (a == 2) ? Bh : Bl;
        const int rowg = ((a < 2) ? mb : nb) + w * 32;
        #pragma unroll
        for (int s = 0; s < 2; ++s) {
            const int idx = a * 2 + s;
            const int lrow = w * 32 + s * 16 + rl;
            gsrc[idx] = base + (size_t)(rowg + s * 16 + rl) * DD + kb * 8;
            lof[idx] = a * 8192 + lrow * 64 + ((kb ^ (rl & 3)) * 16);
        }
    }

    f32x16 zero = {};
    f32x16 acc[2][2];
    #pragma unroll
    for (int i = 0; i < 2; ++i)
        #pragma unroll
        for (int j = 0; j < 2; ++j) acc[i][j] = zero;

    uint4 r[8];
    #pragma unroll
    for (int q = 0; q < 8; ++q) r[q] = *reinterpret_cast<const uint4*>(gsrc[q]);

    for (int t = 0; t < 8; ++t) {          // K chunks of 32
        __syncthreads();                   // previous compute done
        #pragma unroll
        for (int q = 0; q < 8; ++q) *reinterpret_cast<uint4*>(smem + lof[q]) = r[q];
        __syncthreads();                   // LDS ready
        if (t < 7) {                       // prefetch next chunk (overlaps MFMA)
            #pragma unroll
            for (int q = 0; q < 8; ++q)
                r[q] = *reinterpret_cast<const uint4*>(gsrc[q] + (t + 1) * 32);
        }
        #pragma unroll
        for (int tt = 0; tt < 2; ++tt) {   // two K=16 steps
            bf16x8 fah[2], fal[2], fbh[2], fbl[2];
            #pragma unroll
            for (int i = 0; i < 2; ++i) {
                const int row = wr * 64 + i * 32 + (lane & 31);
                const int blk = (tt * 2 + (lane >> 5)) ^ (row & 3);
                const int off = row * 64 + blk * 16;
                fah[i] = *reinterpret_cast<const bf16x8*>(smem + off);
                fal[i] = *reinterpret_cast<const bf16x8*>(smem + 8192 + off);
                const int col = wc * 64 + i * 32 + (lane & 31);
                const int blb = (tt * 2 + (lane >> 5)) ^ (col & 3);
                const int ofb = col * 64 + blb * 16;
                fbh[i] = *reinterpret_cast<const bf16x8*>(smem + 16384 + ofb);
                fbl[i] = *reinterpret_cast<const bf16x8*>(smem + 24576 + ofb);
            }
            #pragma unroll
            for (int i = 0; i < 2; ++i)
                #pragma unroll
                for (int j = 0; j < 2; ++j) {
                    acc[i][j] = __builtin_amdgcn_mfma_f32_32x32x16_bf16(
                        fah[i], fbh[j], acc[i][j], 0, 0, 0);
                    acc[i][j] = __builtin_amdgcn_mfma_f32_32x32x16_bf16(
                        fah[i], fbl[j], acc[i][j], 0, 0, 0);
                    acc[i][j] = __builtin_amdgcn_mfma_f32_32x32x16_bf16(
                        fal[i], fbh[j], acc[i][j], 0, 0, 0);
                }
        }
    }

    // ---- epilogue: route sims, 32-lane reduce, block-combine in LDS ----
    __syncthreads();   // all frag reads done; smem is reusable
    float* Ln = reinterpret_cast<float*>(smem);          // [256]
    float* Lp = reinterpret_cast<float*>(smem + 1024);   // [256]

    const int cl0 = clab[nb + wc * 64 + (lane & 31)];
    const int cl1 = clab[nb + wc * 64 + 32 + (lane & 31)];
    #pragma unroll
    for (int i = 0; i < 2; ++i) {
        const int rl0 = wr * 64 + i * 32;
        #pragma unroll
        for (int q = 0; q < 4; ++q) {
            const int4 pc4 = *reinterpret_cast<const int4*>(
                &pos_col[lev * BB + mb + rl0 + 8 * q + 4 * (lane >> 5)]);
            #pragma unroll
            for (int e = 0; e < 4; ++e) {
                const int reg = 4 * q + e;
                const int pcv = (e == 0) ? pc4.x : (e == 1) ? pc4.y : (e == 2) ? pc4.z : pc4.w;
                const float s0 = acc[i][0][reg];
                const float s1 = acc[i][1][reg];
                const bool p0 = (pcv == cl0) && (pcv >= 0);
                const bool p1 = (pcv == cl1) && (pcv >= 0);
                float nm = fmaxf(p0 ? -2.f : s0, p1 ? -2.f : s1);
                float pm = fminf(p0 ? s0 : 2.f, p1 ? s1 : 2.f);
                #pragma unroll
                for (int m = 1; m < 32; m <<= 1) {   // reduce lanes 0..31 / 32..63
                    nm = fmaxf(nm, __shfl_xor(nm, m));
                    pm = fminf(pm, __shfl_xor(pm, m));
                }
                if ((lane & 31) == 0) {
                    const int idx = wc * 128 + rl0 + 8 * q + e + (lane >> 5) * 4;
                    Ln[idx] = nm;
                    Lp[idx] = pm;
                }
            }
        }
    }
    __syncthreads();
    if (tid < 128) {
        const float nm = fmaxf(Ln[tid], Ln[128 + tid]);
        const float pm = fminf(Lp[tid], Lp[128 + tid]);
        pn[(size_t)by * BB + mb + tid] = nm;
        pp[(size_t)by * BB + mb + tid] = pm;
    }
}

// Reduce the 64 column-tile partials per row; per-block partial loss sums.
__global__ __launch_bounds__(256) void finalize1(const float* __restrict__ pn,
                                                 const float* __restrict__ pp,
                                                 float* __restrict__ partials) {
    const int tid = threadIdx.x;
    const int row = blockIdx.x * 256 + tid;
    float nm = -2.f, pm = 2.f;
    for (int y = 0; y < 64; ++y) {
        nm = fmaxf(nm, pn[(size_t)y * BB + row]);
        pm = fminf(pm, pp[(size_t)y * BB + row]);
    }
    float sum = 0.f, cnt = 0.f;
    if (pm < 1.5f) {  // has_pos (has_neg always true: >=8188 negatives/row)
        sum = fmaxf(nm - pm + 0.2f, 0.f);
        cnt = 1.f;
    }
    #pragma unroll
    for (int m = 1; m < 64; m <<= 1) {
        sum += __shfl_xor(sum, m);
        cnt += __shfl_xor(cnt, m);
    }
    __shared__ float s4[4], c4[4];
    if ((tid & 63) == 0) { s4[tid >> 6] = sum; c4[tid >> 6] = cnt; }
    __syncthreads();
    if (tid == 0) {
        partials[blockIdx.x] = s4[0] + s4[1] + s4[2] + s4[3];
        partials[16 + blockIdx.x] = c4[0] + c4[1] + c4[2] + c4[3];
    }
}

__global__ void finalize2(const float* __restrict__ partials, float* __restrict__ out) {
    if (threadIdx.x == 0) {
        float S = 0.f, C = 0.f;
        for (int i = 0; i < 16; ++i) { S += partials[i]; C += partials[16 + i]; }
        out[0] = S / fmaxf(C, 1.f);
    }
}

// ===================== FALLBACK PATH (round-3 fp32, proven) =====================

__global__ __launch_bounds__(256) void inv_norms(const float* __restrict__ src,
                                                 float* __restrict__ dst, int nrows) {
    int row = blockIdx.x * 4 + (threadIdx.x >> 6);
    int lane = threadIdx.x & 63;
    if (row >= nrows) return;
    float4 v = *reinterpret_cast<const float4*>(src + (size_t)row * DD + lane * 4);
    float ss = v.x * v.x + v.y * v.y + v.z * v.z + v.w * v.w;
    #pragma unroll
    for (int m = 1; m < 64; m <<= 1) ss += __shfl_xor(ss, m);
    if (lane == 0) dst[row] = 1.0f / fmaxf(sqrtf(ss), 1e-12f);
}

__global__ __launch_bounds__(256) void prep_fb(const int* __restrict__ labels_per_eps,
                                               const int* __restrict__ local_indices,
                                               int* __restrict__ pos_col,
                                               uint32* __restrict__ ap_key,
                                               uint32* __restrict__ an_key) {
    int t = blockIdx.x * 256 + threadIdx.x;
    int b = t >> 2, l = t & 3;
    pos_col[t] = labels_per_eps[l * NN + local_indices[b]];
    if (t < BB) { ap_key[t] = f2ord(2.0f); an_key[t] = f2ord(-2.0f); }
}

__global__ __launch_bounds__(256, 4) void fp32_main(const float* __restrict__ A,
                                                    const float* __restrict__ Cm,
                                                    const float* __restrict__ inv_a,
                                                    const float* __restrict__ inv_c,
                                                    const int* __restrict__ clab,
                                                    const int* __restrict__ pos_col,
                                                    uint32* __restrict__ ap_key,
                                                    uint32* __restrict__ an_key) {
    __shared__ float4 As[64 * 17];
    __shared__ float4 Bs[16 * 64];
    const int tid = threadIdx.x;
    const int lane = tid & 63;
    const int wv = tid >> 6;
    const int mb = blockIdx.x * 64;
    const int colbase = blockIdx.y * 64;
    const int lev = colbase >> 11;
    const int kgS = tid & 15;
    const int rS = tid >> 4;
    float acc[16];
    #pragma unroll
    for (int r = 0; r < 16; ++r) acc[r] = 0.f;
    for (int kc = 0; kc < DD; kc += 64) {
        __syncthreads();
        #pragma unroll
        for (int i = 0; i < 4; ++i) {
            int r = rS + 16 * i;
            As[r * 17 + kgS] = *reinterpret_cast<const float4*>(
                A + (size_t)(mb + r) * DD + kc + kgS * 4);
            Bs[kgS * 64 + (r ^ (kgS & 7))] = *reinterpret_cast<const float4*>(
                Cm + (size_t)(colbase + r) * DD + kc + kgS * 4);
        }
        __syncthreads();
        #pragma unroll
        for (int kg = 0; kg < 16; ++kg) {
            float4 b = Bs[kg * 64 + (lane ^ (kg & 7))];
            #pragma unroll
            for (int r = 0; r < 16; ++r) {
                float4 a = As[(wv * 16 + r) * 17 + kg];
                acc[r] = fmaf(a.x, b.x, acc[r]);
                acc[r] = fmaf(a.y, b.y, acc[r]);
                acc[r] = fmaf(a.z, b.z, acc[r]);
                acc[r] = fmaf(a.w, b.w, acc[r]);
            }
        }
    }
    const float ic = inv_c[colbase + lane];
    const int cl = clab[colbase + lane];
    const int row0 = mb + wv * 16;
    #pragma unroll
    for (int r = 0; r < 16; ++r) {
        float s = acc[r] * inv_a[row0 + r] * ic;
        int pcr = pos_col[(row0 + r) * LL + lev];
        bool pos = (pcr == cl) && (pcr >= 0);
        float nm = pos ? -2.f : s;
        #pragma unroll
        for (int m = 1; m < 64; m <<= 1) nm = fmaxf(nm, __shfl_xor(nm, m));
        if (lane == 0) atomicMax(&an_key[row0 + r], f2ord(nm));
        if (pos) atomicMin(&ap_key[row0 + r], f2ord(s));
    }
}

__global__ __launch_bounds__(256) void fb_finalize(const uint32* __restrict__ ap_key,
                                                   const uint32* __restrict__ an_key,
                                                   float* __restrict__ out) {
    int tid = threadIdx.x;
    float sum = 0.f, cnt = 0.f;
    for (int b = tid; b < BB; b += 256) {
        float ap = ord2f(ap_key[b]);
        float an = ord2f(an_key[b]);
        if (ap < 1.5f) { sum += fmaxf(an - ap + 0.2f, 0.f); cnt += 1.f; }
    }
    #pragma unroll
    for (int m = 1; m < 64; m <<= 1) { sum += __shfl_xor(sum, m); cnt += __shfl_xor(cnt, m); }
    __shared__ float s4[4], c4[4];
    int w = tid >> 6;
    if ((tid & 63) == 0) { s4[w] = sum; c4[w] = cnt; }
    __syncthreads();
    if (tid == 0) {
        out[0] = (s4[0] + s4[1] + s4[2] + s4[3]) / fmaxf(c4[0] + c4[1] + c4[2] + c4[3], 1.f);
    }
}

// ================================ launch ================================

extern "C" void kernel_launch(void* const* d_in, const int* in_sizes, int n_in,
                              void* d_out, int out_size, void* d_ws, size_t ws_size,
                              hipStream_t stream) {
    const float* anchors         = (const float*)d_in[0];   // B*D
    const float* centroids       = (const float*)d_in[1];   // L*C*D
    const int*   centroid_labels = (const int*)d_in[2];     // L*C
    const int*   labels_per_eps  = (const int*)d_in[3];     // L*N
    const int*   local_indices   = (const int*)d_in[4];     // B
    float* out = (float*)d_out;

    const size_t MB = 1024 * 1024;
    if (ws_size >= 15 * MB) {
        // fast-path workspace layout (byte offsets)
        char* ws = (char*)d_ws;
        unsigned short* Ah = (unsigned short*)(ws);                 // 2 MB
        unsigned short* Al = (unsigned short*)(ws + 2 * MB);        // 2 MB
        unsigned short* Ch = (unsigned short*)(ws + 4 * MB);        // 4 MB
        unsigned short* Cl = (unsigned short*)(ws + 8 * MB);        // 4 MB
        int*   pos_col = (int*)(ws + 12 * MB);                      // 64 KB ([L][B])
        float* pn = (float*)(ws + 12 * MB + 256 * 1024);            // 1 MB [64][B]
        float* pp = (float*)(ws + 13 * MB + 256 * 1024);            // 1 MB
        float* partials = (float*)(ws + 14 * MB + 256 * 1024);      // 32 floats

        convert_rows<<<BB / 4, 256, 0, stream>>>(anchors, Ah, Al, BB);
        convert_rows<<<(LL * CC) / 4, 256, 0, stream>>>(centroids, Ch, Cl, LL * CC);
        prep_pos<<<(BB * LL) / 256, 256, 0, stream>>>(labels_per_eps, local_indices, pos_col);
        mfma_main<<<2048, 256, 0, stream>>>(Ah, Al, Ch, Cl, centroid_labels,
                                            pos_col, pn, pp);
        finalize1<<<16, 256, 0, stream>>>(pn, pp, partials);
        finalize2<<<1, 64, 0, stream>>>(partials, out);
    } else {
        // fallback: round-3 fp32 path (~150 KB ws)
        float*  inv_a  = (float*)d_ws;
        float*  inv_c  = inv_a + BB;
        int*    pos_col = (int*)(inv_c + LL * CC);
        uint32* ap_key = (uint32*)(pos_col + BB * LL);
        uint32* an_key = ap_key + BB;

        inv_norms<<<BB / 4, 256, 0, stream>>>(anchors, inv_a, BB);
        inv_norms<<<(LL * CC) / 4, 256, 0, stream>>>(centroids, inv_c, LL * CC);
        prep_fb<<<(BB * LL) / 256, 256, 0, stream>>>(labels_per_eps, local_indices,
                                                     pos_col, ap_key, an_key);
        fp32_main<<<dim3(BB / 64, 128), 256, 0, stream>>>(anchors, centroids, inv_a, inv_c,
                                                          centroid_labels, pos_col,
                                                          ap_key, an_key);
        fb_finalize<<<1, 256, 0, stream>>>(ap_key, an_key, out);
    }
}

// Round 5
// 148.609 us; speedup vs baseline: 5.6739x; 1.6719x over previous
//
#include <hip/hip_runtime.h>
#include <hip/hip_bf16.h>

// Problem constants (from reference)
#define BB 4096
#define DD 256
#define LL 4
#define CC 2048
#define NN 100000

typedef unsigned int uint32;

using f32x16 = __attribute__((ext_vector_type(16))) float;
using bf16x8 = __attribute__((ext_vector_type(8))) __bf16;

// async global->LDS, 16B per lane. LDS dest is wave-uniform base + lane*16
// (linear); swizzle is applied on the per-lane GLOBAL source address (m173).
#define GLD16(g, l)                                                        \
    __builtin_amdgcn_global_load_lds(                                      \
        (const __attribute__((address_space(1))) unsigned int*)(g),        \
        (__attribute__((address_space(3))) unsigned int*)(l), 16, 0, 0)

__device__ __forceinline__ uint32 f2ord(float f) {
    uint32 u = __float_as_uint(f);
    return (u & 0x80000000u) ? ~u : (u | 0x80000000u);
}
__device__ __forceinline__ float ord2f(uint32 u) {
    u = (u & 0x80000000u) ? (u & 0x7FFFFFFFu) : ~u;
    return __uint_as_float(u);
}
__device__ __forceinline__ unsigned short bf16bits(float f) {
    __hip_bfloat16 h = __float2bfloat16(f);
    unsigned short b;
    __builtin_memcpy(&b, &h, 2);
    return b;
}

// ============================ FAST PATH (MFMA) ============================

// One launch: blocks [0,1024) normalize+split anchors, [1024,3072) centroids,
// [3072,3136) gather positive labels into [L][B].
__global__ __launch_bounds__(256) void prep_all(const float* __restrict__ anchors,
                                                const float* __restrict__ centroids,
                                                const int* __restrict__ lpe,
                                                const int* __restrict__ li,
                                                unsigned short* __restrict__ Ah,
                                                unsigned short* __restrict__ Al,
                                                unsigned short* __restrict__ Ch,
                                                unsigned short* __restrict__ Cl,
                                                int* __restrict__ pos_col) {
    const int bid = blockIdx.x;
    if (bid >= 3072) {  // prep_pos
        int t = (bid - 3072) * 256 + threadIdx.x;  // 0..16383
        int l = t >> 12, b = t & 4095;
        pos_col[l * BB + b] = lpe[l * NN + li[b]];
        return;
    }
    const bool is_a = (bid < 1024);
    const float* src = is_a ? anchors : centroids;
    unsigned short* hi = is_a ? Ah : Ch;
    unsigned short* lo = is_a ? Al : Cl;
    const int rb = is_a ? bid : (bid - 1024);
    int row = rb * 4 + (threadIdx.x >> 6);
    int lane = threadIdx.x & 63;
    float4 v = *reinterpret_cast<const float4*>(src + (size_t)row * DD + lane * 4);
    float ss = v.x * v.x + v.y * v.y + v.z * v.z + v.w * v.w;
    #pragma unroll
    for (int m = 1; m < 64; m <<= 1) ss += __shfl_xor(ss, m);
    float inv = 1.0f / fmaxf(sqrtf(ss), 1e-12f);
    float y0 = v.x * inv, y1 = v.y * inv, y2 = v.z * inv, y3 = v.w * inv;
    ushort4 h, l;
    h.x = bf16bits(y0); l.x = bf16bits(y0 - __bfloat162float(__float2bfloat16(y0)));
    h.y = bf16bits(y1); l.y = bf16bits(y1 - __bfloat162float(__float2bfloat16(y1)));
    h.z = bf16bits(y2); l.z = bf16bits(y2 - __bfloat162float(__float2bfloat16(y2)));
    h.w = bf16bits(y3); l.w = bf16bits(y3 - __bfloat162float(__float2bfloat16(y3)));
    *reinterpret_cast<ushort4*>(hi + (size_t)row * DD + lane * 4) = h;
    *reinterpret_cast<ushort4*>(lo + (size_t)row * DD + lane * 4) = l;
}

// Fused 3-product (hi/lo error-compensated) MFMA GEMM + pos-min / neg-max.
// Block tile 128x128, BK=32, 4 waves 2x2, wave tile 64x64 (2x2 frags of
// 32x32x16 bf16). Staging: global_load_lds width-16, wave w stages array w
// (Ah/Al/Ch/Cl chunk = 8KB = 8 x 1KB issues). LDS layout per array:
// [128 rows][4 x 16B blocks], physical blk = logical ^ ((row>>1)&3):
//  - staging: linear lane*16 dest (required by global_load_lds), inverse
//    swizzle folded into per-lane global src block = (lane&3)^((lane>>3)&3);
//  - frag reads: 8 consecutive rows hit all 8 16B-granules -> conflict-free
//    (round-4's blk^(row&3) only hit 4 of 8 -> 2-way conflict, 1.26e7 cycles).
// No register prefetch (round-4's r[8] spilled: 7x128B x 512K thr = 470MB
// scratch writes = the observed WRITE_SIZE).
__global__ __launch_bounds__(256, 4) void mfma_main(
    const unsigned short* __restrict__ Ah, const unsigned short* __restrict__ Al,
    const unsigned short* __restrict__ Bh, const unsigned short* __restrict__ Bl,
    const int* __restrict__ clab, const int* __restrict__ pos_col,
    float* __restrict__ pn, float* __restrict__ pp) {
    __shared__ __align__(16) char smem[32768];

    const int tid = threadIdx.x;
    const int lane = tid & 63;
    const int w = tid >> 6;            // wave 0..3
    const int wr = w >> 1, wc = w & 1; // 2x2 wave grid

    // XCD supertile swizzle (2048 % 8 == 0, bijective)
    const int bid = blockIdx.x;
    const int xcd = bid & 7, inner = bid >> 3;
    const int bx = (xcd & 1) * 16 + (inner & 15);   // 0..31 (M tiles)
    const int by = (xcd >> 1) * 16 + (inner >> 4);  // 0..63 (N tiles)
    const int mb = bx * 128, nb = by * 128;
    const int lev = nb >> 11;

    // ---- staging: wave w owns one array; per-lane pre-swizzled global src ----
    const unsigned short* arr = (w == 0) ? Ah : (w == 1) ? Al : (w == 2) ? Bh : Bl;
    const int pbase = (w < 2) ? mb : nb;
    const int sblk = (lane & 3) ^ ((lane >> 3) & 3);  // inverse swizzle (involution)
    const unsigned short* gbase =
        arr + (size_t)(pbase + (lane >> 2)) * DD + sblk * 8;
    char* lbase = smem + w * 8192;

    f32x16 zero = {};
    f32x16 acc[2][2];
    #pragma unroll
    for (int i = 0; i < 2; ++i)
        #pragma unroll
        for (int j = 0; j < 2; ++j) acc[i][j] = zero;

    const int hw = lane >> 5;           // half-wave (k-group)
    const int l31 = lane & 31;
    const int bswz = (lane >> 1) & 3;   // ((row>>1)&3) for our row patterns

    for (int t = 0; t < 8; ++t) {        // K chunks of 32
        __syncthreads();                 // chunk t-1 reads done
        #pragma unroll
        for (int s = 0; s < 8; ++s)
            GLD16(gbase + s * 16 * DD + t * 32, lbase + s * 1024);
        __syncthreads();                 // vmcnt(0) drained by barrier semantics

        #pragma unroll
        for (int tt = 0; tt < 2; ++tt) { // two K=16 steps
            const int phys = (((tt * 2 + hw) ^ bswz) << 4);
            bf16x8 fah[2], fal[2], fbh[2], fbl[2];
            #pragma unroll
            for (int i = 0; i < 2; ++i) {
                const int ra = (wr * 64 + i * 32 + l31) * 64 + phys;
                fah[i] = *reinterpret_cast<const bf16x8*>(smem + ra);
                fal[i] = *reinterpret_cast<const bf16x8*>(smem + 8192 + ra);
                const int rb2 = (wc * 64 + i * 32 + l31) * 64 + phys;
                fbh[i] = *reinterpret_cast<const bf16x8*>(smem + 16384 + rb2);
                fbl[i] = *reinterpret_cast<const bf16x8*>(smem + 24576 + rb2);
            }
            #pragma unroll
            for (int i = 0; i < 2; ++i)
                #pragma unroll
                for (int j = 0; j < 2; ++j) {
                    acc[i][j] = __builtin_amdgcn_mfma_f32_32x32x16_bf16(
                        fah[i], fbh[j], acc[i][j], 0, 0, 0);
                    acc[i][j] = __builtin_amdgcn_mfma_f32_32x32x16_bf16(
                        fah[i], fbl[j], acc[i][j], 0, 0, 0);
                    acc[i][j] = __builtin_amdgcn_mfma_f32_32x32x16_bf16(
                        fal[i], fbh[j], acc[i][j], 0, 0, 0);
                }
        }
    }

    // ---- epilogue: route sims, 32-lane reduce, block-combine in LDS ----
    __syncthreads();   // all frag reads done; smem reusable
    float* Ln = reinterpret_cast<float*>(smem);          // [256]
    float* Lp = reinterpret_cast<float*>(smem + 1024);   // [256]

    const int cl0 = clab[nb + wc * 64 + l31];
    const int cl1 = clab[nb + wc * 64 + 32 + l31];
    #pragma unroll
    for (int i = 0; i < 2; ++i) {
        const int rl0 = wr * 64 + i * 32;
        #pragma unroll
        for (int q = 0; q < 4; ++q) {
            const int4 pc4 = *reinterpret_cast<const int4*>(
                &pos_col[lev * BB + mb + rl0 + 8 * q + 4 * hw]);
            #pragma unroll
            for (int e = 0; e < 4; ++e) {
                const int reg = 4 * q + e;
                const int pcv = (e == 0) ? pc4.x : (e == 1) ? pc4.y : (e == 2) ? pc4.z : pc4.w;
                const float s0 = acc[i][0][reg];
                const float s1 = acc[i][1][reg];
                const bool p0 = (pcv == cl0) && (pcv >= 0);
                const bool p1 = (pcv == cl1) && (pcv >= 0);
                float nm = fmaxf(p0 ? -2.f : s0, p1 ? -2.f : s1);
                float pm = fminf(p0 ? s0 : 2.f, p1 ? s1 : 2.f);
                #pragma unroll
                for (int m = 1; m < 32; m <<= 1) {   // reduce lanes 0..31 / 32..63
                    nm = fmaxf(nm, __shfl_xor(nm, m));
                    pm = fminf(pm, __shfl_xor(pm, m));
                }
                if (l31 == 0) {
                    const int idx = wc * 128 + rl0 + 8 * q + e + hw * 4;
                    Ln[idx] = nm;
                    Lp[idx] = pm;
                }
            }
        }
    }
    __syncthreads();
    if (tid < 128) {
        const float nm = fmaxf(Ln[tid], Ln[128 + tid]);
        const float pm = fminf(Lp[tid], Lp[128 + tid]);
        pn[(size_t)by * BB + mb + tid] = nm;
        pp[(size_t)by * BB + mb + tid] = pm;
    }
}

// Reduce the 64 column-tile partials per row; per-block partial loss sums.
__global__ __launch_bounds__(256) void finalize1(const float* __restrict__ pn,
                                                 const float* __restrict__ pp,
                                                 float* __restrict__ partials) {
    const int tid = threadIdx.x;
    const int row = blockIdx.x * 256 + tid;
    float nm = -2.f, pm = 2.f;
    for (int y = 0; y < 64; ++y) {
        nm = fmaxf(nm, pn[(size_t)y * BB + row]);
        pm = fminf(pm, pp[(size_t)y * BB + row]);
    }
    float sum = 0.f, cnt = 0.f;
    if (pm < 1.5f) {  // has_pos (has_neg always true: >=8188 negatives/row)
        sum = fmaxf(nm - pm + 0.2f, 0.f);
        cnt = 1.f;
    }
    #pragma unroll
    for (int m = 1; m < 64; m <<= 1) {
        sum += __shfl_xor(sum, m);
        cnt += __shfl_xor(cnt, m);
    }
    __shared__ float s4[4], c4[4];
    if ((tid & 63) == 0) { s4[tid >> 6] = sum; c4[tid >> 6] = cnt; }
    __syncthreads();
    if (tid == 0) {
        partials[blockIdx.x] = s4[0] + s4[1] + s4[2] + s4[3];
        partials[16 + blockIdx.x] = c4[0] + c4[1] + c4[2] + c4[3];
    }
}

__global__ void finalize2(const float* __restrict__ partials, float* __restrict__ out) {
    if (threadIdx.x == 0) {
        float S = 0.f, C = 0.f;
        for (int i = 0; i < 16; ++i) { S += partials[i]; C += partials[16 + i]; }
        out[0] = S / fmaxf(C, 1.f);
    }
}

// ===================== FALLBACK PATH (round-3 fp32, proven) =====================

__global__ __launch_bounds__(256) void inv_norms(const float* __restrict__ src,
                                                 float* __restrict__ dst, int nrows) {
    int row = blockIdx.x * 4 + (threadIdx.x >> 6);
    int lane = threadIdx.x & 63;
    if (row >= nrows) return;
    float4 v = *reinterpret_cast<const float4*>(src + (size_t)row * DD + lane * 4);
    float ss = v.x * v.x + v.y * v.y + v.z * v.z + v.w * v.w;
    #pragma unroll
    for (int m = 1; m < 64; m <<= 1) ss += __shfl_xor(ss, m);
    if (lane == 0) dst[row] = 1.0f / fmaxf(sqrtf(ss), 1e-12f);
}

__global__ __launch_bounds__(256) void prep_fb(const int* __restrict__ labels_per_eps,
                                               const int* __restrict__ local_indices,
                                               int* __restrict__ pos_col,
                                               uint32* __restrict__ ap_key,
                                               uint32* __restrict__ an_key) {
    int t = blockIdx.x * 256 + threadIdx.x;
    int b = t >> 2, l = t & 3;
    pos_col[t] = labels_per_eps[l * NN + local_indices[b]];
    if (t < BB) { ap_key[t] = f2ord(2.0f); an_key[t] = f2ord(-2.0f); }
}

__global__ __launch_bounds__(256, 4) void fp32_main(const float* __restrict__ A,
                                                    const float* __restrict__ Cm,
                                                    const float* __restrict__ inv_a,
                                                    const float* __restrict__ inv_c,
                                                    const int* __restrict__ clab,
                                                    const int* __restrict__ pos_col,
                                                    uint32* __restrict__ ap_key,
                                                    uint32* __restrict__ an_key) {
    __shared__ float4 As[64 * 17];
    __shared__ float4 Bs[16 * 64];
    const int tid = threadIdx.x;
    const int lane = tid & 63;
    const int wv = tid >> 6;
    const int mb = blockIdx.x * 64;
    const int colbase = blockIdx.y * 64;
    const int lev = colbase >> 11;
    const int kgS = tid & 15;
    const int rS = tid >> 4;
    float acc[16];
    #pragma unroll
    for (int r = 0; r < 16; ++r) acc[r] = 0.f;
    for (int kc = 0; kc < DD; kc += 64) {
        __syncthreads();
        #pragma unroll
        for (int i = 0; i < 4; ++i) {
            int r = rS + 16 * i;
            As[r * 17 + kgS] = *reinterpret_cast<const float4*>(
                A + (size_t)(mb + r) * DD + kc + kgS * 4);
            Bs[kgS * 64 + (r ^ (kgS & 7))] = *reinterpret_cast<const float4*>(
                Cm + (size_t)(colbase + r) * DD + kc + kgS * 4);
        }
        __syncthreads();
        #pragma unroll
        for (int kg = 0; kg < 16; ++kg) {
            float4 b = Bs[kg * 64 + (lane ^ (kg & 7))];
            #pragma unroll
            for (int r = 0; r < 16; ++r) {
                float4 a = As[(wv * 16 + r) * 17 + kg];
                acc[r] = fmaf(a.x, b.x, acc[r]);
                acc[r] = fmaf(a.y, b.y, acc[r]);
                acc[r] = fmaf(a.z, b.z, acc[r]);
                acc[r] = fmaf(a.w, b.w, acc[r]);
            }
        }
    }
    const float ic = inv_c[colbase + lane];
    const int cl = clab[colbase + lane];
    const int row0 = mb + wv * 16;
    #pragma unroll
    for (int r = 0; r < 16; ++r) {
        float s = acc[r] * inv_a[row0 + r] * ic;
        int pcr = pos_col[(row0 + r) * LL + lev];
        bool pos = (pcr == cl) && (pcr >= 0);
        float nm = pos ? -2.f : s;
        #pragma unroll
        for (int m = 1; m < 64; m <<= 1) nm = fmaxf(nm, __shfl_xor(nm, m));
        if (lane == 0) atomicMax(&an_key[row0 + r], f2ord(nm));
        if (pos) atomicMin(&ap_key[row0 + r], f2ord(s));
    }
}

__global__ __launch_bounds__(256) void fb_finalize(const uint32* __restrict__ ap_key,
                                                   const uint32* __restrict__ an_key,
                                                   float* __restrict__ out) {
    int tid = threadIdx.x;
    float sum = 0.f, cnt = 0.f;
    for (int b = tid; b < BB; b += 256) {
        float ap = ord2f(ap_key[b]);
        float an = ord2f(an_key[b]);
        if (ap < 1.5f) { sum += fmaxf(an - ap + 0.2f, 0.f); cnt += 1.f; }
    }
    #pragma unroll
    for (int m = 1; m < 64; m <<= 1) { sum += __shfl_xor(sum, m); cnt += __shfl_xor(cnt, m); }
    __shared__ float s4[4], c4[4];
    int w = tid >> 6;
    if ((tid & 63) == 0) { s4[w] = sum; c4[w] = cnt; }
    __syncthreads();
    if (tid == 0) {
        out[0] = (s4[0] + s4[1] + s4[2] + s4[3]) / fmaxf(c4[0] + c4[1] + c4[2] + c4[3], 1.f);
    }
}

// ================================ launch ================================

extern "C" void kernel_launch(void* const* d_in, const int* in_sizes, int n_in,
                              void* d_out, int out_size, void* d_ws, size_t ws_size,
                              hipStream_t stream) {
    const float* anchors         = (const float*)d_in[0];   // B*D
    const float* centroids       = (const float*)d_in[1];   // L*C*D
    const int*   centroid_labels = (const int*)d_in[2];     // L*C
    const int*   labels_per_eps  = (const int*)d_in[3];     // L*N
    const int*   local_indices   = (const int*)d_in[4];     // B
    float* out = (float*)d_out;

    const size_t MB = 1024 * 1024;
    if (ws_size >= 15 * MB) {
        // fast-path workspace layout (byte offsets)
        char* ws = (char*)d_ws;
        unsigned short* Ah = (unsigned short*)(ws);                 // 2 MB
        unsigned short* Al = (unsigned short*)(ws + 2 * MB);        // 2 MB
        unsigned short* Ch = (unsigned short*)(ws + 4 * MB);        // 4 MB
        unsigned short* Cl = (unsigned short*)(ws + 8 * MB);        // 4 MB
        int*   pos_col = (int*)(ws + 12 * MB);                      // 64 KB ([L][B])
        float* pn = (float*)(ws + 12 * MB + 256 * 1024);            // 1 MB [64][B]
        float* pp = (float*)(ws + 13 * MB + 256 * 1024);            // 1 MB
        float* partials = (float*)(ws + 14 * MB + 256 * 1024);      // 32 floats

        prep_all<<<3136, 256, 0, stream>>>(anchors, centroids, labels_per_eps,
                                           local_indices, Ah, Al, Ch, Cl, pos_col);
        mfma_main<<<2048, 256, 0, stream>>>(Ah, Al, Ch, Cl, centroid_labels,
                                            pos_col, pn, pp);
        finalize1<<<16, 256, 0, stream>>>(pn, pp, partials);
        finalize2<<<1, 64, 0, stream>>>(partials, out);
    } else {
        // fallback: round-3 fp32 path (~150 KB ws)
        float*  inv_a  = (float*)d_ws;
        float*  inv_c  = inv_a + BB;
        int*    pos_col = (int*)(inv_c + LL * CC);
        uint32* ap_key = (uint32*)(pos_col + BB * LL);
        uint32* an_key = ap_key + BB;

        inv_norms<<<BB / 4, 256, 0, stream>>>(anchors, inv_a, BB);
        inv_norms<<<(LL * CC) / 4, 256, 0, stream>>>(centroids, inv_c, LL * CC);
        prep_fb<<<(BB * LL) / 256, 256, 0, stream>>>(labels_per_eps, local_indices,
                                                     pos_col, ap_key, an_key);
        fp32_main<<<dim3(BB / 64, 128), 256, 0, stream>>>(anchors, centroids, inv_a, inv_c,
                                                          centroid_labels, pos_col,
                                                          ap_key, an_key);
        fb_finalize<<<1, 256, 0, stream>>>(ap_key, an_key, out);
    }
}